// Round 4
// baseline (38.640 us; speedup 1.0000x reference)
//
#include <hip/hip_runtime.h>
#include <math.h>

#define BATCH 32
#define NATOM 512
#define NNBH  256
#define NIN   256
#define NH    128

typedef __attribute__((ext_vector_type(8))) short bf16x8;
typedef __attribute__((ext_vector_type(4))) float f32x4;

__device__ __forceinline__ short f2bf(float f) {
    union { float f; unsigned u; } v; v.f = f;
    unsigned r = v.u + 0x7FFFu + ((v.u >> 16) & 1u);   // RNE
    return (short)(r >> 16);
}

// ---------------- Pass 0: pack W1 (f32 [256][128]) into MFMA B-frag layout ----------------
// layout: [kb(8)][n(8)][lane(64)][h(8)]  where k = kb*32 + (lane>>4)*8 + h, j = n*16 + (lane&15)
__global__ __launch_bounds__(256) void pack_w1(const float* __restrict__ W1,
                                               short* __restrict__ W1p) {
    int t = blockIdx.x * 256 + threadIdx.x;           // 0..32767
    int h    = t & 7;
    int lane = (t >> 3) & 63;
    int n    = (t >> 9) & 7;
    int kb   = t >> 12;
    int k = kb * 32 + (lane >> 4) * 8 + h;
    int j = n * 16 + (lane & 15);
    W1p[t] = f2bf(W1[k * NH + j]);
}

// ---------------- Pass 1: contrib = ssp(rep@W1+b1)@W2+b2 via MFMA -> [B*A, 2] ----------------
__global__ __launch_bounds__(512, 4) void mlp_mfma(
    const float* __restrict__ rep,    // [16384, 256]
    const short* __restrict__ W1p,    // packed bf16
    const float* __restrict__ b1,     // [128]
    const float* __restrict__ W2,     // [128, 2]
    const float* __restrict__ b2,     // [2]
    float* __restrict__ contrib)      // [16384, 2]
{
    __shared__ short sA[32][264];          // bf16 A tile, padded
    __shared__ float part[4][32][2];       // per-npair partial contribs

    const int tid    = threadIdx.x;
    const int lane   = tid & 63;
    const int wave   = tid >> 6;           // 0..7
    const int rstrip = wave & 1;
    const int npair  = wave >> 1;          // 0..3
    const int rowBase = blockIdx.x * 32;
    const int r0 = lane & 15;
    const int kg = lane >> 4;

    // ---- stage 32 rows of rep -> bf16 LDS ----
    {
        const int r  = tid >> 4;
        const int c0 = (tid & 15) * 16;
        const float4* src = (const float4*)(rep + (size_t)(rowBase + r) * NIN + c0);
        const float4 v0 = src[0], v1 = src[1], v2 = src[2], v3 = src[3];
        bf16x8 h0, h1;
        h0[0] = f2bf(v0.x); h0[1] = f2bf(v0.y); h0[2] = f2bf(v0.z); h0[3] = f2bf(v0.w);
        h0[4] = f2bf(v1.x); h0[5] = f2bf(v1.y); h0[6] = f2bf(v1.z); h0[7] = f2bf(v1.w);
        h1[0] = f2bf(v2.x); h1[1] = f2bf(v2.y); h1[2] = f2bf(v2.z); h1[3] = f2bf(v2.w);
        h1[4] = f2bf(v3.x); h1[5] = f2bf(v3.y); h1[6] = f2bf(v3.z); h1[7] = f2bf(v3.w);
        *(bf16x8*)&sA[r][c0]     = h0;
        *(bf16x8*)&sA[r][c0 + 8] = h1;
    }
    __syncthreads();

    f32x4 acc[2];
    acc[0] = (f32x4){0.f, 0.f, 0.f, 0.f};
    acc[1] = (f32x4){0.f, 0.f, 0.f, 0.f};

    #pragma unroll
    for (int kb = 0; kb < 8; ++kb) {
        const bf16x8 af = *(const bf16x8*)&sA[rstrip * 16 + r0][kb * 32 + kg * 8];
        const bf16x8 bf0 = *(const bf16x8*)(W1p + ((size_t)(kb * 8 + npair * 2 + 0) * 64 + lane) * 8);
        const bf16x8 bf1 = *(const bf16x8*)(W1p + ((size_t)(kb * 8 + npair * 2 + 1) * 64 + lane) * 8);
        acc[0] = __builtin_amdgcn_mfma_f32_16x16x32_bf16(af, bf0, acc[0], 0, 0, 0);
        acc[1] = __builtin_amdgcn_mfma_f32_16x16x32_bf16(af, bf1, acc[1], 0, 0, 0);
    }

    float b1v[2], w20[2], w21[2];
    #pragma unroll
    for (int nn = 0; nn < 2; ++nn) {
        const int j = (npair * 2 + nn) * 16 + r0;
        b1v[nn] = b1[j];
        const float2 w = *(const float2*)(W2 + j * 2);
        w20[nn] = w.x; w21[nn] = w.y;
    }

    float c0[4], c1[4];
    #pragma unroll
    for (int reg = 0; reg < 4; ++reg) {
        float s0 = 0.f, s1 = 0.f;
        #pragma unroll
        for (int nn = 0; nn < 2; ++nn) {
            const float z = acc[nn][reg] + b1v[nn];
            const float hv = fmaxf(z, 0.f) + log1pf(expf(-fabsf(z))) - 0.6931471805599453f;
            s0 = fmaf(hv, w20[nn], s0);
            s1 = fmaf(hv, w21[nn], s1);
        }
        c0[reg] = s0; c1[reg] = s1;
    }

    #pragma unroll
    for (int m = 8; m >= 1; m >>= 1) {
        #pragma unroll
        for (int reg = 0; reg < 4; ++reg) {
            c0[reg] += __shfl_xor(c0[reg], m, 64);
            c1[reg] += __shfl_xor(c1[reg], m, 64);
        }
    }

    if (r0 == 0) {
        #pragma unroll
        for (int reg = 0; reg < 4; ++reg) {
            const int lr = rstrip * 16 + kg * 4 + reg;
            part[npair][lr][0] = c0[reg];
            part[npair][lr][1] = c1[reg];
        }
    }
    __syncthreads();

    if (tid < 64) {
        const int r = tid >> 1;
        const int c = tid & 1;
        const float s = part[0][r][c] + part[1][r][c] + part[2][r][c] + part[3][r][c] + b2[c];
        contrib[(size_t)(rowBase + r) * 2 + c] = s;
    }
}

// ---------------- Pass 2: LDS-staged gathers. Block = 16 atoms of one batch. ----------------
// grid: BATCH*32 = 1024 blocks x 256 threads (4 waves); wave handles 4 atoms sequentially.
__global__ __launch_bounds__(256) void pair_kernel(
    const float* __restrict__ positions,  // [B, A, 3]
    const int*   __restrict__ neighbors,  // [B, A, N]
    const float* __restrict__ nbh_mask,   // [B, A, N]
    const float* __restrict__ atom_mask,  // [B, A]
    const float* __restrict__ contrib,    // [B*A, 2]
    float* __restrict__ partials)         // [1024, 9]
{
    __shared__ float sp[NATOM * 3];       // 6 KB, flat copy of posB
    __shared__ float sc[NATOM * 2];       // 4 KB, flat copy of ctrB
    __shared__ float sw[4][9];

    const int tid   = threadIdx.x;
    const int wave  = tid >> 6;
    const int lane  = tid & 63;
    const int b     = blockIdx.x >> 5;            // batch
    const int chunk = blockIdx.x & 31;            // 16-atom chunk within batch

    const float* posB = positions + (size_t)b * NATOM * 3;
    const float* ctrB = contrib   + (size_t)b * NATOM * 2;

    // stage tables (flat, no repack)
    {
        const float4* ps = (const float4*)posB;
        float4* pd = (float4*)sp;
        pd[tid] = ps[tid];                          // 256 * 16B = 4 KB
        if (tid < 128) pd[256 + tid] = ps[256 + tid];
        const float4* cs = (const float4*)ctrB;
        ((float4*)sc)[tid] = cs[tid];               // 4 KB
    }
    __syncthreads();

    float acc9[9];
    #pragma unroll
    for (int i = 0; i < 9; ++i) acc9[i] = 0.f;

    #pragma unroll
    for (int s = 0; s < 4; ++s) {
        const int a = chunk * 16 + wave * 4 + s;    // atom within batch
        const float px = sp[a * 3 + 0];
        const float py = sp[a * 3 + 1];
        const float pz = sp[a * 3 + 2];
        const size_t nbase = ((size_t)b * NATOM + a) * NNBH;

        const int4   idx4 = *(const int4*)(neighbors + nbase + lane * 4);
        const float4 m4   = *(const float4*)(nbh_mask + nbase + lane * 4);
        const int   idxs[4] = {idx4.x, idx4.y, idx4.z, idx4.w};
        const float ms[4]   = {m4.x, m4.y, m4.z, m4.w};

        float dipx = 0.f, dipy = 0.f, dipz = 0.f;
        float fx = 0.f, fy = 0.f, fz = 0.f;

        #pragma unroll
        for (int i = 0; i < 4; ++i) {
            const int idx = idxs[i];
            const float m = ms[i];
            const float qx = sp[idx * 3 + 0];
            const float qy = sp[idx * 3 + 1];
            const float qz = sp[idx * 3 + 2];
            const float n1 = sc[idx * 2 + 0];
            const float n2 = sc[idx * 2 + 1];
            const float dx = qx - px, dy = qy - py, dz = qz - pz;
            const float d2 = dx * dx + dy * dy + dz * dz;
            const float dist = sqrtf(d2);
            const float md = dist * d2 * m + (1.f - m);   // dist^3*m + (1-m)
            const float nc1 = n1 * m;
            const float nc2 = n2 * m / md;
            dipx = fmaf(dx, nc1, dipx);
            dipy = fmaf(dy, nc1, dipy);
            dipz = fmaf(dz, nc1, dipz);
            fx = fmaf(dx, nc2, fx);
            fy = fmaf(dy, nc2, fy);
            fz = fmaf(dz, nc2, fz);
        }

        #pragma unroll
        for (int off = 32; off >= 1; off >>= 1) {
            dipx += __shfl_down(dipx, off, 64);
            dipy += __shfl_down(dipy, off, 64);
            dipz += __shfl_down(dipz, off, 64);
            fx   += __shfl_down(fx,   off, 64);
            fy   += __shfl_down(fy,   off, 64);
            fz   += __shfl_down(fz,   off, 64);
        }

        if (lane == 0) {
            float norm = sqrtf(fx * fx + fy * fy + fz * fz);
            norm += (norm < 1e-10f) ? 1.f : 0.f;
            const float inv = 1.f / norm;
            const float f0 = fx * inv, f1 = fy * inv, f2 = fz * inv;
            const float am = atom_mask[(size_t)b * NATOM + a];
            const float d0 = dipx, d1 = dipy, d2v = dipz;
            acc9[0] = fmaf(d0 * f0, am, acc9[0]);
            acc9[1] = fmaf(0.5f * (d0 * f1 + d1 * f0), am, acc9[1]);
            acc9[2] = fmaf(0.5f * (d0 * f2 + d2v * f0), am, acc9[2]);
            acc9[3] = fmaf(0.5f * (d1 * f0 + d0 * f1), am, acc9[3]);
            acc9[4] = fmaf(d1 * f1, am, acc9[4]);
            acc9[5] = fmaf(0.5f * (d1 * f2 + d2v * f1), am, acc9[5]);
            acc9[6] = fmaf(0.5f * (d2v * f0 + d0 * f2), am, acc9[6]);
            acc9[7] = fmaf(0.5f * (d2v * f1 + d1 * f2), am, acc9[7]);
            acc9[8] = fmaf(d2v * f2, am, acc9[8]);
        }
    }

    if (lane == 0) {
        #pragma unroll
        for (int i = 0; i < 9; ++i) sw[wave][i] = acc9[i];
    }
    __syncthreads();
    if (tid < 9) {
        partials[(size_t)blockIdx.x * 9 + tid] =
            sw[0][tid] + sw[1][tid] + sw[2][tid] + sw[3][tid];
    }
}

// ---------------- Pass 3: fold 32 block-partials per batch -> out [B,9] ----------------
__global__ __launch_bounds__(320) void reduce_kernel(
    const float* __restrict__ partials,  // [B*32, 9]
    float* __restrict__ out)             // [B, 9]
{
    __shared__ float s[32][9];
    const int b = blockIdx.x;
    const int t = threadIdx.x;
    if (t < 288) {
        const int i = t / 9;
        const int j = t - i * 9;
        s[i][j] = partials[(size_t)(b * 32 + i) * 9 + j];
    }
    __syncthreads();
    if (t < 9) {
        float acc = 0.f;
        #pragma unroll
        for (int i = 0; i < 32; ++i) acc += s[i][t];
        out[(size_t)b * 9 + t] = acc;
    }
}

extern "C" void kernel_launch(void* const* d_in, const int* in_sizes, int n_in,
                              void* d_out, int out_size, void* d_ws, size_t ws_size,
                              hipStream_t stream) {
    const float* positions = (const float*)d_in[0];   // [B,A,3]
    const float* rep       = (const float*)d_in[1];   // [B,A,256]
    const int*   neighbors = (const int*)d_in[2];     // [B,A,N]
    const float* nbh_mask  = (const float*)d_in[3];   // [B,A,N]
    const float* atom_mask = (const float*)d_in[4];   // [B,A]
    const float* W1        = (const float*)d_in[5];   // [256,128]
    const float* b1        = (const float*)d_in[6];   // [128]
    const float* W2        = (const float*)d_in[7];   // [128,2]
    const float* b2        = (const float*)d_in[8];   // [2]
    float* out = (float*)d_out;

    float* contrib  = (float*)d_ws;                               // 16384*2 f32 = 128 KB
    float* partials = contrib + (size_t)BATCH * NATOM * 2;        // 1024*9 f32 = 36 KB
    short* W1p      = (short*)(partials + 1024 * 9);              // 32768 bf16 = 64 KB

    const int nRows = BATCH * NATOM;                              // 16384

    pack_w1<<<128, 256, 0, stream>>>(W1, W1p);
    mlp_mfma<<<nRows / 32, 512, 0, stream>>>(rep, W1p, b1, W2, b2, contrib);
    pair_kernel<<<BATCH * 32, 256, 0, stream>>>(positions, neighbors, nbh_mask, atom_mask,
                                                contrib, partials);
    reduce_kernel<<<BATCH, 320, 0, stream>>>(partials, out);
}

// Round 5
// 37.180 us; speedup vs baseline: 1.0393x; 1.0393x over previous
//
#include <hip/hip_runtime.h>
#include <math.h>

#define BATCH 32
#define NATOM 512
#define NNBH  256
#define NIN   256
#define NH    128

typedef __attribute__((ext_vector_type(8))) short bf16x8;
typedef __attribute__((ext_vector_type(4))) float f32x4;

__device__ __forceinline__ short f2bf(float f) {
    union { float f; unsigned u; } v; v.f = f;
    unsigned r = v.u + 0x7FFFu + ((v.u >> 16) & 1u);   // RNE
    return (short)(r >> 16);
}

// ---------------- Pass 0: pack W1 (f32 [256][128]) into MFMA B-frag layout ----------------
// layout: [kb(8)][n(8)][lane(64)][h(8)]  where k = kb*32 + (lane>>4)*8 + h, j = n*16 + (lane&15)
__global__ __launch_bounds__(256) void pack_w1(const float* __restrict__ W1,
                                               short* __restrict__ W1p) {
    int t = blockIdx.x * 256 + threadIdx.x;           // 0..32767
    int h    = t & 7;
    int lane = (t >> 3) & 63;
    int n    = (t >> 9) & 7;
    int kb   = t >> 12;
    int k = kb * 32 + (lane >> 4) * 8 + h;
    int j = n * 16 + (lane & 15);
    W1p[t] = f2bf(W1[k * NH + j]);
}

// ---------------- Pass 1: contrib = ssp(rep@W1+b1)@W2+b2 via MFMA -> [B*A, 2] ----------------
// (identical to R3/R4)
__global__ __launch_bounds__(512, 4) void mlp_mfma(
    const float* __restrict__ rep,    // [16384, 256]
    const short* __restrict__ W1p,    // packed bf16
    const float* __restrict__ b1,     // [128]
    const float* __restrict__ W2,     // [128, 2]
    const float* __restrict__ b2,     // [2]
    float* __restrict__ contrib)      // [16384, 2]
{
    __shared__ short sA[32][264];          // bf16 A tile, padded
    __shared__ float part[4][32][2];       // per-npair partial contribs

    const int tid    = threadIdx.x;
    const int lane   = tid & 63;
    const int wave   = tid >> 6;           // 0..7
    const int rstrip = wave & 1;
    const int npair  = wave >> 1;          // 0..3
    const int rowBase = blockIdx.x * 32;
    const int r0 = lane & 15;
    const int kg = lane >> 4;

    // ---- stage 32 rows of rep -> bf16 LDS ----
    {
        const int r  = tid >> 4;
        const int c0 = (tid & 15) * 16;
        const float4* src = (const float4*)(rep + (size_t)(rowBase + r) * NIN + c0);
        const float4 v0 = src[0], v1 = src[1], v2 = src[2], v3 = src[3];
        bf16x8 h0, h1;
        h0[0] = f2bf(v0.x); h0[1] = f2bf(v0.y); h0[2] = f2bf(v0.z); h0[3] = f2bf(v0.w);
        h0[4] = f2bf(v1.x); h0[5] = f2bf(v1.y); h0[6] = f2bf(v1.z); h0[7] = f2bf(v1.w);
        h1[0] = f2bf(v2.x); h1[1] = f2bf(v2.y); h1[2] = f2bf(v2.z); h1[3] = f2bf(v2.w);
        h1[4] = f2bf(v3.x); h1[5] = f2bf(v3.y); h1[6] = f2bf(v3.z); h1[7] = f2bf(v3.w);
        *(bf16x8*)&sA[r][c0]     = h0;
        *(bf16x8*)&sA[r][c0 + 8] = h1;
    }
    __syncthreads();

    f32x4 acc[2];
    acc[0] = (f32x4){0.f, 0.f, 0.f, 0.f};
    acc[1] = (f32x4){0.f, 0.f, 0.f, 0.f};

    #pragma unroll
    for (int kb = 0; kb < 8; ++kb) {
        const bf16x8 af = *(const bf16x8*)&sA[rstrip * 16 + r0][kb * 32 + kg * 8];
        const bf16x8 bf0 = *(const bf16x8*)(W1p + ((size_t)(kb * 8 + npair * 2 + 0) * 64 + lane) * 8);
        const bf16x8 bf1 = *(const bf16x8*)(W1p + ((size_t)(kb * 8 + npair * 2 + 1) * 64 + lane) * 8);
        acc[0] = __builtin_amdgcn_mfma_f32_16x16x32_bf16(af, bf0, acc[0], 0, 0, 0);
        acc[1] = __builtin_amdgcn_mfma_f32_16x16x32_bf16(af, bf1, acc[1], 0, 0, 0);
    }

    float b1v[2], w20[2], w21[2];
    #pragma unroll
    for (int nn = 0; nn < 2; ++nn) {
        const int j = (npair * 2 + nn) * 16 + r0;
        b1v[nn] = b1[j];
        const float2 w = *(const float2*)(W2 + j * 2);
        w20[nn] = w.x; w21[nn] = w.y;
    }

    float c0[4], c1[4];
    #pragma unroll
    for (int reg = 0; reg < 4; ++reg) {
        float s0 = 0.f, s1 = 0.f;
        #pragma unroll
        for (int nn = 0; nn < 2; ++nn) {
            const float z = acc[nn][reg] + b1v[nn];
            const float hv = fmaxf(z, 0.f) + log1pf(expf(-fabsf(z))) - 0.6931471805599453f;
            s0 = fmaf(hv, w20[nn], s0);
            s1 = fmaf(hv, w21[nn], s1);
        }
        c0[reg] = s0; c1[reg] = s1;
    }

    #pragma unroll
    for (int m = 8; m >= 1; m >>= 1) {
        #pragma unroll
        for (int reg = 0; reg < 4; ++reg) {
            c0[reg] += __shfl_xor(c0[reg], m, 64);
            c1[reg] += __shfl_xor(c1[reg], m, 64);
        }
    }

    if (r0 == 0) {
        #pragma unroll
        for (int reg = 0; reg < 4; ++reg) {
            const int lr = rstrip * 16 + kg * 4 + reg;
            part[npair][lr][0] = c0[reg];
            part[npair][lr][1] = c1[reg];
        }
    }
    __syncthreads();

    if (tid < 64) {
        const int r = tid >> 1;
        const int c = tid & 1;
        const float s = part[0][r][c] + part[1][r][c] + part[2][r][c] + part[3][r][c] + b2[c];
        contrib[(size_t)(rowBase + r) * 2 + c] = s;
    }
}

// ---------------- Pass 2: R1-exact pair kernel (scalar coalesced loads, L1 gathers) ----------------
__global__ __launch_bounds__(256) void pair_kernel(
    const float* __restrict__ positions,  // [B, A, 3]
    const int*   __restrict__ neighbors,  // [B, A, N]
    const float* __restrict__ nbh_mask,   // [B, A, N]
    const float* __restrict__ atom_mask,  // [B, A]
    const float* __restrict__ contrib,    // [B*A, 2]
    float* __restrict__ partials)         // [gridDim.x, 9]
{
    const int tid  = threadIdx.x;
    const int wave = tid >> 6;
    const int lane = tid & 63;
    const int atom = blockIdx.x * 4 + wave;       // global atom idx
    const int b = atom >> 9;                      // / NATOM
    const int a = atom & (NATOM - 1);

    const float* posB = positions + (size_t)b * NATOM * 3;
    const float* ctrB = contrib   + (size_t)b * NATOM * 2;
    const float px = posB[a * 3 + 0];
    const float py = posB[a * 3 + 1];
    const float pz = posB[a * 3 + 2];
    const size_t nbase = (size_t)atom * NNBH;

    float dipx = 0.f, dipy = 0.f, dipz = 0.f;
    float fx = 0.f, fy = 0.f, fz = 0.f;

    #pragma unroll
    for (int i = 0; i < NNBH / 64; ++i) {
        const int n = lane + i * 64;
        const int idx = neighbors[nbase + n];
        const float m = nbh_mask[nbase + n];
        const float qx = posB[idx * 3 + 0];
        const float qy = posB[idx * 3 + 1];
        const float qz = posB[idx * 3 + 2];
        const float dx = qx - px, dy = qy - py, dz = qz - pz;
        const float d2 = dx * dx + dy * dy + dz * dz;
        const float dist = sqrtf(d2);
        const float md = dist * d2 * m + (1.f - m);     // dist^3*m + (1-m)
        const float nc1 = ctrB[idx * 2 + 0] * m;
        const float nc2 = ctrB[idx * 2 + 1] * m / md;
        dipx = fmaf(dx, nc1, dipx);
        dipy = fmaf(dy, nc1, dipy);
        dipz = fmaf(dz, nc1, dipz);
        fx = fmaf(dx, nc2, fx);
        fy = fmaf(dy, nc2, fy);
        fz = fmaf(dz, nc2, fz);
    }

    #pragma unroll
    for (int off = 32; off >= 1; off >>= 1) {
        dipx += __shfl_down(dipx, off, 64);
        dipy += __shfl_down(dipy, off, 64);
        dipz += __shfl_down(dipz, off, 64);
        fx   += __shfl_down(fx,   off, 64);
        fy   += __shfl_down(fy,   off, 64);
        fz   += __shfl_down(fz,   off, 64);
    }

    __shared__ float sw[4][9];
    if (lane == 0) {
        float norm = sqrtf(fx * fx + fy * fy + fz * fz);
        norm += (norm < 1e-10f) ? 1.f : 0.f;
        const float inv = 1.f / norm;
        const float f0 = fx * inv, f1 = fy * inv, f2 = fz * inv;
        const float am = atom_mask[(size_t)b * NATOM + a];
        const float d0 = dipx, d1 = dipy, d2v = dipz;
        sw[wave][0] = d0 * f0 * am;
        sw[wave][1] = 0.5f * (d0 * f1 + d1 * f0) * am;
        sw[wave][2] = 0.5f * (d0 * f2 + d2v * f0) * am;
        sw[wave][3] = 0.5f * (d1 * f0 + d0 * f1) * am;
        sw[wave][4] = d1 * f1 * am;
        sw[wave][5] = 0.5f * (d1 * f2 + d2v * f1) * am;
        sw[wave][6] = 0.5f * (d2v * f0 + d0 * f2) * am;
        sw[wave][7] = 0.5f * (d2v * f1 + d1 * f2) * am;
        sw[wave][8] = d2v * f2 * am;
    }
    __syncthreads();
    if (tid < 9) {
        partials[(size_t)blockIdx.x * 9 + tid] =
            sw[0][tid] + sw[1][tid] + sw[2][tid] + sw[3][tid];
    }
}

// ---------------- Pass 3: fold 128 block-partials per batch -> out [B,9] ----------------
__global__ __launch_bounds__(128) void reduce_kernel(
    const float* __restrict__ partials,  // [B*128, 9]
    float* __restrict__ out)             // [B, 9]
{
    __shared__ float s[128][9];
    const int b = blockIdx.x;
    const int t = threadIdx.x;
    const float* p = partials + (size_t)b * 128 * 9;
    #pragma unroll
    for (int i = 0; i < 9; ++i) s[t][i] = p[(size_t)t * 9 + i];
    __syncthreads();
    if (t < 9) {
        float acc = 0.f;
        #pragma unroll 16
        for (int i = 0; i < 128; ++i) acc += s[i][t];
        out[(size_t)b * 9 + t] = acc;
    }
}

extern "C" void kernel_launch(void* const* d_in, const int* in_sizes, int n_in,
                              void* d_out, int out_size, void* d_ws, size_t ws_size,
                              hipStream_t stream) {
    const float* positions = (const float*)d_in[0];   // [B,A,3]
    const float* rep       = (const float*)d_in[1];   // [B,A,256]
    const int*   neighbors = (const int*)d_in[2];     // [B,A,N]
    const float* nbh_mask  = (const float*)d_in[3];   // [B,A,N]
    const float* atom_mask = (const float*)d_in[4];   // [B,A]
    const float* W1        = (const float*)d_in[5];   // [256,128]
    const float* b1        = (const float*)d_in[6];   // [128]
    const float* W2        = (const float*)d_in[7];   // [128,2]
    const float* b2        = (const float*)d_in[8];   // [2]
    float* out = (float*)d_out;

    float* contrib  = (float*)d_ws;                               // 16384*2 f32 = 128 KB
    float* partials = contrib + (size_t)BATCH * NATOM * 2;        // 4096*9 f32 = 144 KB
    short* W1p      = (short*)(partials + 4096 * 9);              // 32768 bf16 = 64 KB

    const int nRows = BATCH * NATOM;                              // 16384

    pack_w1<<<128, 256, 0, stream>>>(W1, W1p);
    mlp_mfma<<<nRows / 32, 512, 0, stream>>>(rep, W1p, b1, W2, b2, contrib);
    pair_kernel<<<nRows / 4, 256, 0, stream>>>(positions, neighbors, nbh_mask, atom_mask,
                                               contrib, partials);
    reduce_kernel<<<BATCH, 128, 0, stream>>>(partials, out);
}